// Round 5
// baseline (63.037 us; speedup 1.0000x reference)
//
#include <hip/hip_runtime.h>

#define NN 8192
#define GAMMA 0.1f

typedef float v2f __attribute__((ext_vector_type(2)));
typedef float v4f __attribute__((ext_vector_type(4)));

// prep: one thread per row (x rows: gid<NN, y rows: gid>=NN).
// Gathers raw feat = [W[row.u], H[row.v]], wave-reduces min/max, writes
// per-wave partials to ws (no atomics). x-rows also compute pred & w.
__global__ __launch_bounds__(256) void prep_kernel(
    const int* __restrict__ x, const int* __restrict__ y,
    const float* __restrict__ W, const float* __restrict__ H,
    const float* __restrict__ nue, const float* __restrict__ nie,
    const float* __restrict__ l1w, const float* __restrict__ l1b,
    const float* __restrict__ l2w,
    const float* __restrict__ mfu, const float* __restrict__ mfi,
    float* __restrict__ pred, float* __restrict__ wout,
    float* __restrict__ pmn, float* __restrict__ pmx)
{
    int gid = blockIdx.x * 256 + threadIdx.x;
    bool isx = gid < NN;
    int i = isx ? gid : gid - NN;
    const int* idx = isx ? x : y;
    int iu = idx[2 * i], iv = idx[2 * i + 1];

    const float4* wp = (const float4*)(W + (size_t)iu * 8);
    float4 w0 = wp[0], w1 = wp[1];
    const float4* hp = (const float4*)(H + (size_t)iv * 8);
    float4 h0 = hp[0], h1 = hp[1];

    float f[16];
    f[0] = w0.x; f[1] = w0.y; f[2] = w0.z; f[3] = w0.w;
    f[4] = w1.x; f[5] = w1.y; f[6] = w1.z; f[7] = w1.w;
    f[8] = h0.x; f[9] = h0.y; f[10] = h0.z; f[11] = h0.w;
    f[12] = h1.x; f[13] = h1.y; f[14] = h1.z; f[15] = h1.w;

    float mn = f[0], mx = f[0];
#pragma unroll
    for (int k = 1; k < 16; k++) { mn = fminf(mn, f[k]); mx = fmaxf(mx, f[k]); }
#pragma unroll
    for (int off = 1; off < 64; off <<= 1) {
        mn = fminf(mn, __shfl_xor(mn, off));
        mx = fmaxf(mx, __shfl_xor(mx, off));
    }
    if ((threadIdx.x & 63) == 0) {
        int wid = gid >> 6;   // 0..255; waves 0..127 x-side, 128..255 y-side
        pmn[wid] = mn;
        pmx[wid] = mx;
    }

    if (isx) {
        // NCF MLP: z = [ncf_user_emb[u], ncf_item_emb[v]] (16)
        const float4* up = (const float4*)(nue + (size_t)iu * 8);
        float4 u0 = up[0], u1 = up[1];
        const float4* ip = (const float4*)(nie + (size_t)iv * 8);
        float4 i0 = ip[0], i1 = ip[1];
        float z[16];
        z[0] = u0.x; z[1] = u0.y; z[2] = u0.z; z[3] = u0.w;
        z[4] = u1.x; z[5] = u1.y; z[6] = u1.z; z[7] = u1.w;
        z[8] = i0.x; z[9] = i0.y; z[10] = i0.z; z[11] = i0.w;
        z[12] = i1.x; z[13] = i1.y; z[14] = i1.z; z[15] = i1.w;

        float p = 0.f;
#pragma unroll
        for (int k = 0; k < 8; k++) {
            float h = l1b[k];
#pragma unroll
            for (int m = 0; m < 16; m++) h = fmaf(z[m], l1w[k * 16 + m], h);
            h = fmaxf(h, 0.f);
            p = fmaf(h, l2w[k], p);
        }
        pred[i] = p;

        // MF dot: sum(mf_user_emb[u] * mf_item_emb[v])
        const float4* ap = (const float4*)(mfu + (size_t)iu * 8);
        float4 a0 = ap[0], a1 = ap[1];
        const float4* bp = (const float4*)(mfi + (size_t)iv * 8);
        float4 b0 = bp[0], b1 = bp[1];
        float wv = a0.x * b0.x + a0.y * b0.y + a0.z * b0.z + a0.w * b0.w
                 + a1.x * b1.x + a1.y * b1.y + a1.z * b1.z + a1.w * b1.w;
        wout[i] = wv;
    }
}

// Fused normalize + kernel-matrix kernel.
// Per block: reduce min/max partials (4 waves, shfl), gather+normalize
// 32 fy rows into LDS (scaled by CC) and 4 fx cols into regs (scaled by
// -2), then K[i][j] = exp2(-sqrt(max(nyc[i]+nxc[j]+dot, 0))) where the
// CC=(gamma*log2 e)^2 factor is pre-folded into fy/nyc/nxc.
__global__ __launch_bounds__(256) void kexp_kernel(
    const int* __restrict__ x, const int* __restrict__ y,
    const float* __restrict__ W, const float* __restrict__ H,
    const float* __restrict__ pmn, const float* __restrict__ pmx,
    float* __restrict__ K)
{
    __shared__ float sfy[512];
    __shared__ float sny[32];
    __shared__ float sred[4];
    int tid = threadIdx.x;
    int ib = blockIdx.y * 32;
    int jb = blockIdx.x * 1024;
    const float CC = 2.0813689894397856e-2f;  // (GAMMA * log2(e))^2

    // phase 1: reduce 128 partials/side; wave0:xmin wave1:xmax wave2:ymin wave3:ymax
    {
        int wv = tid >> 6, ln = tid & 63;
        const float* psrc = (wv & 1) ? pmx : pmn;
        int base = (wv >> 1) * 128;
        float u0 = psrc[base + ln], u1 = psrc[base + ln + 64];
        float v = (wv & 1) ? fmaxf(u0, u1) : fminf(u0, u1);
#pragma unroll
        for (int off = 1; off < 64; off <<= 1) {
            float o = __shfl_xor(v, off);
            v = (wv & 1) ? fmaxf(v, o) : fminf(v, o);
        }
        if (ln == 0) sred[wv] = v;
    }
    __syncthreads();
    float cx = sred[0] / (sred[1] - sred[0]);
    float cy = sred[2] / (sred[3] - sred[2]);

    // phase 2: fy rows -> LDS (scaled by CC), row norms -> sny (scaled by CC)
    if (tid < 32) {
        int r = ib + tid;
        int iu = y[2 * r], iv = y[2 * r + 1];
        const float4* wp = (const float4*)(W + (size_t)iu * 8);
        float4 w0 = wp[0], w1 = wp[1];
        const float4* hp = (const float4*)(H + (size_t)iv * 8);
        float4 h0 = hp[0], h1 = hp[1];
        float f[16];
        f[0] = w0.x; f[1] = w0.y; f[2] = w0.z; f[3] = w0.w;
        f[4] = w1.x; f[5] = w1.y; f[6] = w1.z; f[7] = w1.w;
        f[8] = h0.x; f[9] = h0.y; f[10] = h0.z; f[11] = h0.w;
        f[12] = h1.x; f[13] = h1.y; f[14] = h1.z; f[15] = h1.w;
        float s = 0.f;
        float g[16];
#pragma unroll
        for (int k = 0; k < 16; k++) {
            g[k] = (f[k] - cy) * (1.f / 16.f);
            s = fmaf(g[k], g[k], s);
        }
        float4* dv = (float4*)(sfy + tid * 16);
        dv[0] = make_float4(g[0] * CC, g[1] * CC, g[2] * CC, g[3] * CC);
        dv[1] = make_float4(g[4] * CC, g[5] * CC, g[6] * CC, g[7] * CC);
        dv[2] = make_float4(g[8] * CC, g[9] * CC, g[10] * CC, g[11] * CC);
        dv[3] = make_float4(g[12] * CC, g[13] * CC, g[14] * CC, g[15] * CC);
        sny[tid] = s * CC;
    }

    // phase 3: fx cols -> regs (scaled by -2), col norms (scaled by CC)
    int j0 = jb + tid * 4;
    v2f a[4][8];
    float nxr[4];
    {
        int4 xi0 = *(const int4*)(x + 2 * j0);
        int4 xi1 = *(const int4*)(x + 2 * j0 + 4);
        int iu[4] = {xi0.x, xi0.z, xi1.x, xi1.z};
        int iv[4] = {xi0.y, xi0.w, xi1.y, xi1.w};
#pragma unroll
        for (int c = 0; c < 4; c++) {
            const float4* wp = (const float4*)(W + (size_t)iu[c] * 8);
            float4 w0 = wp[0], w1 = wp[1];
            const float4* hp = (const float4*)(H + (size_t)iv[c] * 8);
            float4 h0 = hp[0], h1 = hp[1];
            float f[16];
            f[0] = w0.x; f[1] = w0.y; f[2] = w0.z; f[3] = w0.w;
            f[4] = w1.x; f[5] = w1.y; f[6] = w1.z; f[7] = w1.w;
            f[8] = h0.x; f[9] = h0.y; f[10] = h0.z; f[11] = h0.w;
            f[12] = h1.x; f[13] = h1.y; f[14] = h1.z; f[15] = h1.w;
            float s = 0.f;
#pragma unroll
            for (int k = 0; k < 8; k++) {
                float g0 = (f[2 * k] - cx) * (1.f / 16.f);
                float g1 = (f[2 * k + 1] - cx) * (1.f / 16.f);
                s = fmaf(g0, g0, s);
                s = fmaf(g1, g1, s);
                a[c][k] = (v2f){-2.f * g0, -2.f * g1};
            }
            nxr[c] = s * CC;
        }
    }
    __syncthreads();

    const float4* sfy4 = (const float4*)sfy;

#pragma unroll 2
    for (int i = 0; i < 32; i++) {
        float4 q0 = sfy4[i * 4 + 0], q1 = sfy4[i * 4 + 1];
        float4 q2 = sfy4[i * 4 + 2], q3 = sfy4[i * 4 + 3];
        v2f fy[8];
        fy[0] = (v2f){q0.x, q0.y}; fy[1] = (v2f){q0.z, q0.w};
        fy[2] = (v2f){q1.x, q1.y}; fy[3] = (v2f){q1.z, q1.w};
        fy[4] = (v2f){q2.x, q2.y}; fy[5] = (v2f){q2.z, q2.w};
        fy[6] = (v2f){q3.x, q3.y}; fy[7] = (v2f){q3.z, q3.w};
        float nyv = sny[i];
        float r[4];
#pragma unroll
        for (int c2 = 0; c2 < 4; c2++) {
            v2f acc = (v2f){nyv + nxr[c2], 0.f};
#pragma unroll
            for (int k = 0; k < 8; k++)
                acc = __builtin_elementwise_fma(a[c2][k], fy[k], acc);
            float d2 = fmaxf(acc.x + acc.y, 0.f);
            r[c2] = __builtin_amdgcn_exp2f(-__builtin_amdgcn_sqrtf(d2));
        }
        v4f o = (v4f){r[0], r[1], r[2], r[3]};
        __builtin_nontemporal_store(o, (v4f*)(K + (size_t)(ib + i) * NN + j0));
    }
}

extern "C" void kernel_launch(void* const* d_in, const int* in_sizes, int n_in,
                              void* d_out, int out_size, void* d_ws, size_t ws_size,
                              hipStream_t stream) {
    const int* x = (const int*)d_in[0];
    const int* y = (const int*)d_in[1];
    const float* W = (const float*)d_in[2];
    const float* H = (const float*)d_in[3];
    const float* nue = (const float*)d_in[4];
    const float* nie = (const float*)d_in[5];
    const float* l1w = (const float*)d_in[6];
    const float* l1b = (const float*)d_in[7];
    const float* l2w = (const float*)d_in[8];
    const float* mfu = (const float*)d_in[9];
    const float* mfi = (const float*)d_in[10];

    float* out = (float*)d_out;
    float* K = out;
    float* pred = out + (size_t)NN * NN;
    float* wout = pred + NN;

    float* pmn = (float*)d_ws;            // 256 wave partial mins
    float* pmx = pmn + 256;               // 256 wave partial maxs

    hipLaunchKernelGGL(prep_kernel, dim3(64), dim3(256), 0, stream,
                       x, y, W, H, nue, nie, l1w, l1b, l2w, mfu, mfi, pred, wout, pmn, pmx);
    hipLaunchKernelGGL(kexp_kernel, dim3(8, 256), dim3(256), 0, stream,
                       x, y, W, H, pmn, pmx, K);
}